// Round 10
// baseline (207.084 us; speedup 1.0000x reference)
//
#include <hip/hip_runtime.h>

typedef __bf16 bf16_t;
typedef __bf16 bf16x4 __attribute__((ext_vector_type(4)));
typedef __bf16 bf16x8 __attribute__((ext_vector_type(8)));
typedef float  f32x4  __attribute__((ext_vector_type(4)));
typedef float  f32x16 __attribute__((ext_vector_type(16)));
typedef unsigned int u32;

#define MFMA16(a, b, c) __builtin_amdgcn_mfma_f32_16x16x32_bf16((a), (b), (c), 0, 0, 0)
#define MFMA32(a, b, c) __builtin_amdgcn_mfma_f32_32x32x16_bf16((a), (b), (c), 0, 0, 0)

__device__ __forceinline__ void gld_lds16(const bf16_t* g, bf16_t* l) {
  __builtin_amdgcn_global_load_lds((__attribute__((address_space(1))) void*)g,
                                   (__attribute__((address_space(3))) void*)l, 16, 0, 0);
}
__device__ __forceinline__ u32 cvt_pk_bf16(float lo, float hi) {
  u32 r;
  asm("v_cvt_pk_bf16_f32 %0, %1, %2" : "=v"(r) : "v"(lo), "v"(hi));
  return r;
}

// ---------------- prep: x cast (big) ----------------
__global__ void cast_f32_bf16(const float* __restrict__ s, bf16_t* __restrict__ d, int n) {
  int i = (blockIdx.x * blockDim.x + threadIdx.x) * 4;
  if (i >= n) return;
  float4 v = *(const float4*)(s + i);
  bf16x4 o;
  o[0] = (bf16_t)v.x; o[1] = (bf16_t)v.y; o[2] = (bf16_t)v.z; o[3] = (bf16_t)v.w;
  *(bf16x4*)(d + i) = o;
}

// ---------------- prep: all weight casts + bias concat in one launch ----------------
__global__ void prep_w(const float* __restrict__ Wq, const float* __restrict__ Wk,
                       const float* __restrict__ Wv, const float* __restrict__ Wo,
                       const float* __restrict__ bq, const float* __restrict__ bk,
                       const float* __restrict__ bv,
                       bf16_t* __restrict__ wqkv, bf16_t* __restrict__ wob,
                       float* __restrict__ qkvb) {
  const int NW = 768 * 768;
  const int t = blockIdx.x * 256 + threadIdx.x;
  const int i = t * 4;
  if (i < 3 * NW) {
    const float* s; int off;
    if (i < NW)          { s = Wq; off = i; }
    else if (i < 2 * NW) { s = Wk; off = i - NW; }
    else                 { s = Wv; off = i - 2 * NW; }
    float4 v = *(const float4*)(s + off);
    bf16x4 o;
    o[0] = (bf16_t)v.x; o[1] = (bf16_t)v.y; o[2] = (bf16_t)v.z; o[3] = (bf16_t)v.w;
    *(bf16x4*)(wqkv + i) = o;
  } else if (i < 4 * NW) {
    const int off = i - 3 * NW;
    float4 v = *(const float4*)(Wo + off);
    bf16x4 o;
    o[0] = (bf16_t)v.x; o[1] = (bf16_t)v.y; o[2] = (bf16_t)v.z; o[3] = (bf16_t)v.w;
    *(bf16x4*)(wob + off) = o;
  }
  if (t < 2304) qkvb[t] = t < 768 ? bq[t] : (t < 1536 ? bk[t - 768] : bv[t - 1536]);
}

// ---------------- fused QKV GEMM (R9-verified): contiguous staging + chunk-XOR swizzle ----------------
__global__ __launch_bounds__(256) void gemm_qkv(
    const bf16_t* __restrict__ A, const bf16_t* __restrict__ B,
    const float* __restrict__ bias,
    bf16_t* __restrict__ qb, bf16_t* __restrict__ kb2, bf16_t* __restrict__ vtb) {
  __shared__ __align__(16) bf16_t As[128 * 64];
  __shared__ __align__(16) bf16_t Bs[128 * 64];
  const int K = 768;
  const int bm = blockIdx.x, bn = blockIdx.y;
  const int tid = threadIdx.x;
  const int w = tid >> 6, l = tid & 63, lg = l >> 4, ln = l & 15;
  const int wr = w >> 1, wc = w & 1;
  const int lr8 = l >> 3, lc8 = l & 7;
  const int region = (bn * 128) / 768;
  const int ln7 = ln & 7;
  f32x4 acc[4][4] = {};
  for (int kb = 0; kb < K / 64; ++kb) {
    const int k0 = kb * 64;
#pragma unroll
    for (int i = 0; i < 4; ++i) {
      const int row = w * 32 + i * 8 + lr8;
      const int so = k0 + ((lc8 ^ (row & 7)) << 3);     // pre-swizzled source col
      gld_lds16(A + (size_t)(bm * 128 + row) * K + so, As + (w * 32 + i * 8) * 64 + l * 8);
      gld_lds16(B + (size_t)(bn * 128 + row) * K + so, Bs + (w * 32 + i * 8) * 64 + l * 8);
    }
    __syncthreads();
#pragma unroll
    for (int kk = 0; kk < 2; ++kk) {
      bf16x8 af[4], bfr[4];
#pragma unroll
      for (int m = 0; m < 4; ++m) {
        const int jc = ((kk * 4 + lg) ^ ln7) << 3;      // swizzled chunk read
        af[m]  = *(const bf16x8*)(As + (wr * 64 + m * 16 + ln) * 64 + jc);
        bfr[m] = *(const bf16x8*)(Bs + (wc * 64 + m * 16 + ln) * 64 + jc);
      }
      if (region != 2) {
#pragma unroll
        for (int m = 0; m < 4; ++m)
#pragma unroll
          for (int n = 0; n < 4; ++n) acc[m][n] = MFMA16(af[m], bfr[n], acc[m][n]);
      } else {  // C^T for coalesced [B,H,D,T] writes
#pragma unroll
        for (int m = 0; m < 4; ++m)
#pragma unroll
          for (int n = 0; n < 4; ++n) acc[m][n] = MFMA16(bfr[n], af[m], acc[m][n]);
      }
    }
    __syncthreads();
  }
  if (region != 2) {
    const float scl = (region == 0) ? 0.18033688011112042f : 1.0f;  // 0.125*log2(e)
    bf16_t* dst = region == 0 ? qb : kb2;
#pragma unroll
    for (int m = 0; m < 4; ++m)
#pragma unroll
      for (int n = 0; n < 4; ++n)
#pragma unroll
        for (int j = 0; j < 4; ++j) {
          const int gm = bm * 128 + wr * 64 + m * 16 + lg * 4 + j;   // t
          const int gn = bn * 128 + wc * 64 + n * 16 + ln;           // qkv col
          const float v = (acc[m][n][j] + bias[gn]) * scl;
          const int c = gn - region * 768;
          const int bb = gm >> 12, tt = gm & 4095;
          const int hh = c >> 6, d = c & 63;
          dst[((size_t)(bb * 12 + hh) * 4096 + tt) * 64 + d] = (bf16_t)v;
        }
  } else {  // transposed acc: C-row = channel, C-col = t (lanes ln -> consecutive t)
#pragma unroll
    for (int m = 0; m < 4; ++m)
#pragma unroll
      for (int n = 0; n < 4; ++n)
#pragma unroll
        for (int j = 0; j < 4; ++j) {
          const int gn = bn * 128 + wc * 64 + n * 16 + lg * 4 + j;   // qkv col (channel)
          const int gm = bm * 128 + wr * 64 + m * 16 + ln;           // t
          const float v = acc[m][n][j] + bias[gn];
          const int c = gn - 1536;
          const int bb = gm >> 12, tt = gm & 4095;
          const int hh = c >> 6, d = c & 63;
          vtb[((size_t)(bb * 12 + hh) * 64 + d) * 4096 + tt] = (bf16_t)v;
        }
  }
}

// ---------------- flash attention (causal), 4-wave blocks, serial KV sweep ----------------
// 768 blocks (head hb, 128-row qtile qt) x 256 thr = 4 waves (32 q-rows each).
// Each block serially sweeps tiles t = 0..2qt+1, double-buffered 32KB LDS ->
// up to 5 blocks/CU co-resident; barriers sync only 4 waves, other blocks'
// waves desync and fill the VALU/MFMA pipes (convoy fix vs R9's 8-wave lockstep).
// Fragment-major LDS staging + T12 in-register P path (R6/R7-verified).
__global__ __launch_bounds__(256) void attn_fwd(
    const bf16_t* __restrict__ q, const bf16_t* __restrict__ k,
    const bf16_t* __restrict__ vt, bf16_t* __restrict__ y) {
  __shared__ __align__(16) bf16_t Ks[2][4096];
  __shared__ __align__(16) bf16_t Vs[2][4096];

  const int p = blockIdx.x;
  const int xcd = p & 7, slot = p >> 3;        // 96 slots per XCD
  const int hb = xcd + 8 * (slot % 3);         // 3 heads per XCD (L2-resident K/V)
  const int qt = 31 - slot / 3;                // heavy-first
  const int tid = threadIdx.x;
  const int w = tid >> 6, l = tid & 63, lq = l & 31, lh = l >> 5;
  const size_t hbo = (size_t)hb * (4096 * 64);
  const bf16_t* qh = q + hbo;
  const bf16_t* kh = k + hbo;
  const bf16_t* vh = vt + hbo;

  const int q0 = qt * 128 + w * 32;            // wave's first q row
  const int qidx = q0 + lq;                    // this lane's q row
  const int nst = 2 * qt + 2;                  // tiles to sweep

  // staging: thread stages chunks {tid, tid+256} of K and of V (4 x gld_lds16/step)
  const int sr0 = tid & 31,           sc0 = ((((tid >> 6) & 3) << 1) | ((tid >> 5) & 1)) << 3;
  const int sr1 = 32 | (tid & 31),    sc1 = sc0;   // chunk tid+256: bit8 set -> +32 row
  const bf16_t* ks0 = kh + ((size_t)sr0 * 64 + sc0);
  const bf16_t* ks1 = kh + ((size_t)sr1 * 64 + sc1);
  const bf16_t* vs0 = vh + ((size_t)sr0 * 4096 + sc0);
  const bf16_t* vs1 = vh + ((size_t)sr1 * 4096 + sc1);

  // Q fragment (B operand of swapped QK^T): qf[ds][j] = Q[qidx][16*ds+8*lh+j]
  bf16x8 qf[4];
#pragma unroll
  for (int ds = 0; ds < 4; ++ds)
    qf[ds] = *(const bf16x8*)(qh + (size_t)qidx * 64 + 16 * ds + 8 * lh);

  gld_lds16(ks0, &Ks[0][tid * 8]);
  gld_lds16(ks1, &Ks[0][2048 + tid * 8]);
  gld_lds16(vs0, &Vs[0][tid * 8]);
  gld_lds16(vs1, &Vs[0][2048 + tid * 8]);
  __syncthreads();

  f32x16 o0 = {}, o1 = {};
  float lsum = 0.f;

  int cur = 0;
  for (int t = 0; t < nst; ++t) {
    if (t + 1 < nst) {  // prefetch next tile into other buffer
      gld_lds16(ks0 + 4096, &Ks[cur ^ 1][tid * 8]);
      gld_lds16(ks1 + 4096, &Ks[cur ^ 1][2048 + tid * 8]);
      gld_lds16(vs0 + 64, &Vs[cur ^ 1][tid * 8]);
      gld_lds16(vs1 + 64, &Vs[cur ^ 1][2048 + tid * 8]);
    }
    ks0 += 4096; ks1 += 4096; vs0 += 64; vs1 += 64;
    const int kvb = t * 64;
    if (kvb <= q0 + 31) {  // causal: wave needs this tile
      const bool diag = (kvb + 63 > q0);
      const bf16_t* KsW = &Ks[cur][0];
      const bf16_t* VsW = &Vs[cur][0];
      u32 pq[2][8];
#pragma unroll
      for (int kb = 0; kb < 2; ++kb) {
        f32x16 st = {};
        __builtin_amdgcn_s_setprio(1);
#pragma unroll
        for (int ds = 0; ds < 4; ++ds) {
          bf16x8 kf = *(const bf16x8*)(KsW + (kb * 4 + ds) * 512 + l * 8);
          st = MFMA32(kf, qf[ds], st);
        }
        __builtin_amdgcn_s_setprio(0);
        float pv[16];
#pragma unroll
        for (int r = 0; r < 16; ++r) pv[r] = __builtin_amdgcn_exp2f(st[r]);
        if (diag) {
          const int kb0 = kvb + kb * 32 + 4 * lh;
#pragma unroll
          for (int r = 0; r < 16; ++r)
            if (kb0 + (r & 3) + 8 * (r >> 2) > qidx) pv[r] = 0.f;
        }
#pragma unroll
        for (int r = 0; r < 16; ++r) lsum += pv[r];
#pragma unroll
        for (int g = 0; g < 8; ++g) pq[kb][g] = cvt_pk_bf16(pv[2 * g], pv[2 * g + 1]);
#pragma unroll
        for (int ks2 = 0; ks2 < 2; ++ks2) {
          asm("v_permlane32_swap_b32 %0, %1" : "+v"(pq[kb][4 * ks2 + 0]), "+v"(pq[kb][4 * ks2 + 2]));
          asm("v_permlane32_swap_b32 %0, %1" : "+v"(pq[kb][4 * ks2 + 1]), "+v"(pq[kb][4 * ks2 + 3]));
        }
      }
      __builtin_amdgcn_s_setprio(1);
#pragma unroll
      for (int ks = 0; ks < 4; ++ks) {
        bf16x8 pa = *(const bf16x8*)&pq[ks >> 1][(ks & 1) * 4];
        bf16x8 v0 = *(const bf16x8*)(VsW + ks * 512 + l * 8);
        bf16x8 v1 = *(const bf16x8*)(VsW + (4 + ks) * 512 + l * 8);
        o0 = MFMA32(pa, v0, o0);
        o1 = MFMA32(pa, v1, o1);
      }
      __builtin_amdgcn_s_setprio(0);
    }
    __syncthreads();
    cur ^= 1;
  }
  // row sums: lanes l and l+32 hold the two k-halves for q = l&31
  lsum += __shfl_xor(lsum, 32);
  float linv[16];
#pragma unroll
  for (int r = 0; r < 16; ++r)
    linv[r] = 1.0f / __shfl(lsum, (r & 3) + 8 * (r >> 2) + 4 * lh);
  const int b = hb / 12, h = hb - b * 12;
#pragma unroll
  for (int r = 0; r < 16; ++r) {
    const int row = q0 + (r & 3) + 8 * (r >> 2) + 4 * lh;
    bf16_t* yr = y + ((size_t)b * 4096 + row) * 768 + h * 64 + lq;
    yr[0]  = (bf16_t)(o0[r] * linv[r]);
    yr[32] = (bf16_t)(o1[r] * linv[r]);
  }
}

// ---------------- output GEMM: out = y @ Wo^T + bo (fp32), swizzled LDS (R9-verified) ----------------
__global__ __launch_bounds__(256) void gemm_out(
    const bf16_t* __restrict__ A, const bf16_t* __restrict__ B,
    const float* __restrict__ bias, float* __restrict__ out) {
  __shared__ __align__(16) bf16_t As[128 * 64];
  __shared__ __align__(16) bf16_t Bs[128 * 64];
  const int K = 768;
  const int bm = blockIdx.x, bn = blockIdx.y;
  const int tid = threadIdx.x;
  const int w = tid >> 6, l = tid & 63, lg = l >> 4, ln = l & 15;
  const int wr = w >> 1, wc = w & 1;
  const int lr8 = l >> 3, lc8 = l & 7;
  const int ln7 = ln & 7;
  f32x4 acc[4][4] = {};
  for (int kb = 0; kb < K / 64; ++kb) {
    const int k0 = kb * 64;
#pragma unroll
    for (int i = 0; i < 4; ++i) {
      const int row = w * 32 + i * 8 + lr8;
      const int so = k0 + ((lc8 ^ (row & 7)) << 3);
      gld_lds16(A + (size_t)(bm * 128 + row) * K + so, As + (w * 32 + i * 8) * 64 + l * 8);
      gld_lds16(B + (size_t)(bn * 128 + row) * K + so, Bs + (w * 32 + i * 8) * 64 + l * 8);
    }
    __syncthreads();
#pragma unroll
    for (int kk = 0; kk < 2; ++kk) {
      bf16x8 af[4], bfr[4];
#pragma unroll
      for (int m = 0; m < 4; ++m) {
        const int jc = ((kk * 4 + lg) ^ ln7) << 3;
        af[m]  = *(const bf16x8*)(As + (wr * 64 + m * 16 + ln) * 64 + jc);
        bfr[m] = *(const bf16x8*)(Bs + (wc * 64 + m * 16 + ln) * 64 + jc);
      }
#pragma unroll
      for (int m = 0; m < 4; ++m)
#pragma unroll
        for (int n = 0; n < 4; ++n) acc[m][n] = MFMA16(af[m], bfr[n], acc[m][n]);
    }
    __syncthreads();
  }
  const int gn0 = bn * 128 + wc * 64;
#pragma unroll
  for (int m = 0; m < 4; ++m) {
#pragma unroll
    for (int n = 0; n < 4; ++n) {
#pragma unroll
      for (int j = 0; j < 4; ++j) {
        const int gm = bm * 128 + wr * 64 + m * 16 + lg * 4 + j;
        const int gn = gn0 + n * 16 + ln;
        out[(size_t)gm * 768 + gn] = acc[m][n][j] + bias[gn];
      }
    }
  }
}

// ---------------- launch ----------------
extern "C" void kernel_launch(void* const* d_in, const int* in_sizes, int n_in,
                              void* d_out, int out_size, void* d_ws, size_t ws_size,
                              hipStream_t stream) {
  const float* x  = (const float*)d_in[0];
  const float* Wq = (const float*)d_in[1];
  const float* bq = (const float*)d_in[2];
  const float* Wk = (const float*)d_in[3];
  const float* bk = (const float*)d_in[4];
  const float* Wv = (const float*)d_in[5];
  const float* bv = (const float*)d_in[6];
  const float* Wo = (const float*)d_in[7];
  const float* bo = (const float*)d_in[8];
  float* out = (float*)d_out;

  const int M = 8192, C = 768, QKV = 2304;
  bf16_t* xb   = (bf16_t*)d_ws;                    // [8192][768]
  bf16_t* wqkv = xb + (size_t)M * C;               // [2304][768]
  bf16_t* wob  = wqkv + (size_t)QKV * C;           // [768][768]
  float*  qkvb = (float*)(wob + (size_t)C * C);    // [2304]
  bf16_t* qbuf = (bf16_t*)(qkvb + QKV);            // [B,H,T,D] (q pre-scaled)
  bf16_t* kbuf = qbuf + (size_t)M * C;             // [B,H,T,D]
  bf16_t* vtb  = kbuf + (size_t)M * C;             // [B,H,D,T]
  bf16_t* yb   = xb;                               // reuse xb (dead after gemm_qkv)

  cast_f32_bf16<<<6144, 256, 0, stream>>>(x, xb, M * C);
  prep_w<<<2304, 256, 0, stream>>>(Wq, Wk, Wv, Wo, bq, bk, bv, wqkv, wob, qkvb);

  gemm_qkv<<<dim3(64, 18), 256, 0, stream>>>(xb, wqkv, qkvb, qbuf, kbuf, vtb);
  attn_fwd<<<768, 256, 0, stream>>>(qbuf, kbuf, vtb, yb);
  gemm_out<<<dim3(64, 6), 256, 0, stream>>>(yb, wob, bo, out);
}

// Round 12
// 181.483 us; speedup vs baseline: 1.1411x; 1.1411x over previous
//
#include <hip/hip_runtime.h>

typedef __bf16 bf16_t;
typedef __bf16 bf16x4 __attribute__((ext_vector_type(4)));
typedef __bf16 bf16x8 __attribute__((ext_vector_type(8)));
typedef float  f32x4  __attribute__((ext_vector_type(4)));
typedef float  f32x16 __attribute__((ext_vector_type(16)));
typedef unsigned int u32;

#define MFMA16(a, b, c) __builtin_amdgcn_mfma_f32_16x16x32_bf16((a), (b), (c), 0, 0, 0)
#define MFMA32(a, b, c) __builtin_amdgcn_mfma_f32_32x32x16_bf16((a), (b), (c), 0, 0, 0)

__device__ __forceinline__ void gld_lds16(const bf16_t* g, bf16_t* l) {
  __builtin_amdgcn_global_load_lds((__attribute__((address_space(1))) void*)g,
                                   (__attribute__((address_space(3))) void*)l, 16, 0, 0);
}
__device__ __forceinline__ u32 cvt_pk_bf16(float lo, float hi) {
  u32 r;
  asm("v_cvt_pk_bf16_f32 %0, %1, %2" : "=v"(r) : "v"(lo), "v"(hi));
  return r;
}

// ---------------- prep: x cast (big) ----------------
__global__ void cast_f32_bf16(const float* __restrict__ s, bf16_t* __restrict__ d, int n) {
  int i = (blockIdx.x * blockDim.x + threadIdx.x) * 4;
  if (i >= n) return;
  float4 v = *(const float4*)(s + i);
  bf16x4 o;
  o[0] = (bf16_t)v.x; o[1] = (bf16_t)v.y; o[2] = (bf16_t)v.z; o[3] = (bf16_t)v.w;
  *(bf16x4*)(d + i) = o;
}

// ---------------- prep: all weight casts + bias concat in one launch ----------------
__global__ void prep_w(const float* __restrict__ Wq, const float* __restrict__ Wk,
                       const float* __restrict__ Wv, const float* __restrict__ Wo,
                       const float* __restrict__ bq, const float* __restrict__ bk,
                       const float* __restrict__ bv,
                       bf16_t* __restrict__ wqkv, bf16_t* __restrict__ wob,
                       float* __restrict__ qkvb) {
  const int NW = 768 * 768;
  const int t = blockIdx.x * 256 + threadIdx.x;
  const int i = t * 4;
  if (i < 3 * NW) {
    const float* s; int off;
    if (i < NW)          { s = Wq; off = i; }
    else if (i < 2 * NW) { s = Wk; off = i - NW; }
    else                 { s = Wv; off = i - 2 * NW; }
    float4 v = *(const float4*)(s + off);
    bf16x4 o;
    o[0] = (bf16_t)v.x; o[1] = (bf16_t)v.y; o[2] = (bf16_t)v.z; o[3] = (bf16_t)v.w;
    *(bf16x4*)(wqkv + i) = o;
  } else if (i < 4 * NW) {
    const int off = i - 3 * NW;
    float4 v = *(const float4*)(Wo + off);
    bf16x4 o;
    o[0] = (bf16_t)v.x; o[1] = (bf16_t)v.y; o[2] = (bf16_t)v.z; o[3] = (bf16_t)v.w;
    *(bf16x4*)(wob + off) = o;
  }
  if (t < 2304) qkvb[t] = t < 768 ? bq[t] : (t < 1536 ? bk[t - 768] : bv[t - 1536]);
}

// ---------------- fused QKV GEMM: BK=32 double-buffered, 1 barrier/iter ----------------
// LDS[buf][row][c] (c = 16B chunk, 4/row, 128 rows = 512 chunks) holds source chunk
// c^((row>>1)&3). Each thread stages chunks {tid, tid+256} of A and B (full coverage:
// 2*256 = 512 chunks). Note ((row+64)>>1)&3 == ((row>>1)&3), so one swizzle formula
// serves both halves. Fragment read XORs the same -> 2-way banked = free (G4).
// V-region computes C^T (swapped operands) so [B,H,D,T] writes coalesce.
// q pre-scaled by 1/sqrt(64)*log2(e).
__global__ __launch_bounds__(256) void gemm_qkv(
    const bf16_t* __restrict__ A, const bf16_t* __restrict__ B,
    const float* __restrict__ bias,
    bf16_t* __restrict__ qb, bf16_t* __restrict__ kb2, bf16_t* __restrict__ vtb) {
  __shared__ __align__(16) bf16_t As[2][128 * 32];
  __shared__ __align__(16) bf16_t Bs[2][128 * 32];
  const int K = 768, NKB = 24;
  const int bm = blockIdx.x, bn = blockIdx.y;
  const int tid = threadIdx.x;
  const int w = tid >> 6, l = tid & 63, lg = l >> 4, ln = l & 15;
  const int wr = w >> 1, wc = w & 1;
  const int region = (bn * 128) / 768;
  // staging: chunks tid (rows 0..63) and tid+256 (rows 64..127); src col pre-swizzled
  const int srow = tid >> 2, sch = tid & 3;
  const int scol = (sch ^ ((srow >> 1) & 3)) << 3;
  const bf16_t* aSrc0 = A + (size_t)(bm * 128 + srow) * K + scol;
  const bf16_t* aSrc1 = A + (size_t)(bm * 128 + 64 + srow) * K + scol;
  const bf16_t* bSrc0 = B + (size_t)(bn * 128 + srow) * K + scol;
  const bf16_t* bSrc1 = B + (size_t)(bn * 128 + 64 + srow) * K + scol;
  f32x4 acc[4][4] = {};
  gld_lds16(aSrc0, &As[0][tid * 8]);
  gld_lds16(aSrc1, &As[0][(256 + tid) * 8]);
  gld_lds16(bSrc0, &Bs[0][tid * 8]);
  gld_lds16(bSrc1, &Bs[0][(256 + tid) * 8]);
  aSrc0 += 32; aSrc1 += 32; bSrc0 += 32; bSrc1 += 32;
  __syncthreads();
  for (int kb = 0; kb < NKB; ++kb) {
    const int cur = kb & 1;
    if (kb + 1 < NKB) {
      gld_lds16(aSrc0, &As[cur ^ 1][tid * 8]);
      gld_lds16(aSrc1, &As[cur ^ 1][(256 + tid) * 8]);
      gld_lds16(bSrc0, &Bs[cur ^ 1][tid * 8]);
      gld_lds16(bSrc1, &Bs[cur ^ 1][(256 + tid) * 8]);
      aSrc0 += 32; aSrc1 += 32; bSrc0 += 32; bSrc1 += 32;
    }
    bf16x8 af[4], bfr[4];
#pragma unroll
    for (int m = 0; m < 4; ++m) {
      const int ra = wr * 64 + m * 16 + ln;
      const int rb = wc * 64 + m * 16 + ln;
      af[m]  = *(const bf16x8*)(&As[cur][ra * 32 + ((lg ^ ((ra >> 1) & 3)) << 3)]);
      bfr[m] = *(const bf16x8*)(&Bs[cur][rb * 32 + ((lg ^ ((rb >> 1) & 3)) << 3)]);
    }
    if (region != 2) {
#pragma unroll
      for (int m = 0; m < 4; ++m)
#pragma unroll
        for (int n = 0; n < 4; ++n) acc[m][n] = MFMA16(af[m], bfr[n], acc[m][n]);
    } else {  // C^T for coalesced [B,H,D,T] writes
#pragma unroll
      for (int m = 0; m < 4; ++m)
#pragma unroll
        for (int n = 0; n < 4; ++n) acc[m][n] = MFMA16(bfr[n], af[m], acc[m][n]);
    }
    __syncthreads();
  }
  if (region != 2) {
    const float scl = (region == 0) ? 0.18033688011112042f : 1.0f;  // 0.125*log2(e)
    bf16_t* dst = region == 0 ? qb : kb2;
#pragma unroll
    for (int m = 0; m < 4; ++m)
#pragma unroll
      for (int n = 0; n < 4; ++n)
#pragma unroll
        for (int j = 0; j < 4; ++j) {
          const int gm = bm * 128 + wr * 64 + m * 16 + lg * 4 + j;   // t
          const int gn = bn * 128 + wc * 64 + n * 16 + ln;           // qkv col
          const float v = (acc[m][n][j] + bias[gn]) * scl;
          const int c = gn - region * 768;
          const int bb = gm >> 12, tt = gm & 4095;
          const int hh = c >> 6, d = c & 63;
          dst[((size_t)(bb * 12 + hh) * 4096 + tt) * 64 + d] = (bf16_t)v;
        }
  } else {  // transposed acc: C-row = channel, C-col = t (lanes ln -> consecutive t)
#pragma unroll
    for (int m = 0; m < 4; ++m)
#pragma unroll
      for (int n = 0; n < 4; ++n)
#pragma unroll
        for (int j = 0; j < 4; ++j) {
          const int gn = bn * 128 + wc * 64 + n * 16 + lg * 4 + j;   // qkv col (channel)
          const int gm = bm * 128 + wr * 64 + m * 16 + ln;           // t
          const float v = acc[m][n][j] + bias[gn];
          const int c = gn - 1536;
          const int bb = gm >> 12, tt = gm & 4095;
          const int hh = c >> 6, d = c & 63;
          vtb[((size_t)(bb * 12 + hh) * 64 + d) * 4096 + tt] = (bf16_t)v;
        }
  }
}

// ---------------- flash attention (causal), in-block K-split (R9-verified) ----------------
__global__ __launch_bounds__(512) void attn_fwd(
    const bf16_t* __restrict__ q, const bf16_t* __restrict__ k,
    const bf16_t* __restrict__ vt, bf16_t* __restrict__ y) {
  __shared__ __align__(16) unsigned char SMEM[65536];
  bf16_t* Ks = (bf16_t*)SMEM;            // [dbuf][stream][4096]
  bf16_t* Vs = (bf16_t*)(SMEM + 32768);  // [dbuf][stream][4096]
  float*  osh = (float*)SMEM;            // combine: [4][32][64] f32
  float*  lsh = (float*)(SMEM + 32768);  // combine: [4][64] f32

  const int p = blockIdx.x;
  const int xcd = p & 7, slot = p >> 3;        // 96 slots per XCD
  const int hb = xcd + 8 * (slot % 3);         // 3 heads per XCD (L2-resident K/V)
  const int qt = 31 - slot / 3;                // heavy-first
  const int tid = threadIdx.x;
  const int w = tid >> 6, l = tid & 63, lq = l & 31, lh = l >> 5;
  const int wq = w >> 1, wc = w & 1;
  const size_t hbo = (size_t)hb * (4096 * 64);
  const bf16_t* qh = q + hbo;
  const bf16_t* kh = k + hbo;
  const bf16_t* vh = vt + hbo;

  const int q0 = qt * 128 + wq * 32;           // wave's first q row
  const int qidx = q0 + lq;                    // this lane's q row
  const int nst = qt + 1;                      // lockstep steps

  const int sr = ((tid >> 8) << 5) | (tid & 31);
  const int sc = ((((tid >> 6) & 3) << 1) | ((tid >> 5) & 1)) << 3;
  const bf16_t* k0src = kh + ((size_t)sr * 64 + sc);
  const bf16_t* k1src = k0src + 4096;
  const bf16_t* v0src = vh + ((size_t)sr * 4096 + sc);
  const bf16_t* v1src = v0src + 64;

  bf16x8 qf[4];
#pragma unroll
  for (int ds = 0; ds < 4; ++ds)
    qf[ds] = *(const bf16x8*)(qh + (size_t)qidx * 64 + 16 * ds + 8 * lh);

  gld_lds16(k0src, Ks + tid * 8);
  gld_lds16(k1src, Ks + 4096 + tid * 8);
  gld_lds16(v0src, Vs + tid * 8);
  gld_lds16(v1src, Vs + 4096 + tid * 8);
  __syncthreads();

  f32x16 o0 = {}, o1 = {};
  float lsum = 0.f;

  int cur = 0;
  for (int i = 0; i < nst; ++i) {
    if (i + 1 < nst) {
      bf16_t* kd = Ks + (cur ^ 1) * 8192;
      bf16_t* vd = Vs + (cur ^ 1) * 8192;
      gld_lds16(k0src + 8192, kd + tid * 8);
      gld_lds16(k1src + 8192, kd + 4096 + tid * 8);
      gld_lds16(v0src + 128, vd + tid * 8);
      gld_lds16(v1src + 128, vd + 4096 + tid * 8);
    }
    k0src += 8192; k1src += 8192; v0src += 128; v1src += 128;
    const int t = 2 * i + wc;
    if (t * 64 <= q0 + 31) {
      const int kvb = t * 64;
      const bool diag = (kvb + 63 > q0);
      const bf16_t* KsW = Ks + (cur * 2 + wc) * 4096;
      const bf16_t* VsW = Vs + (cur * 2 + wc) * 4096;
      u32 pq[2][8];
#pragma unroll
      for (int kb = 0; kb < 2; ++kb) {
        f32x16 st = {};
        __builtin_amdgcn_s_setprio(1);
#pragma unroll
        for (int ds = 0; ds < 4; ++ds) {
          bf16x8 kf = *(const bf16x8*)(KsW + (kb * 4 + ds) * 512 + l * 8);
          st = MFMA32(kf, qf[ds], st);
        }
        __builtin_amdgcn_s_setprio(0);
        float pv[16];
#pragma unroll
        for (int r = 0; r < 16; ++r) pv[r] = __builtin_amdgcn_exp2f(st[r]);
        if (diag) {
          const int kb0 = kvb + kb * 32 + 4 * lh;
#pragma unroll
          for (int r = 0; r < 16; ++r)
            if (kb0 + (r & 3) + 8 * (r >> 2) > qidx) pv[r] = 0.f;
        }
#pragma unroll
        for (int r = 0; r < 16; ++r) lsum += pv[r];
#pragma unroll
        for (int g = 0; g < 8; ++g) pq[kb][g] = cvt_pk_bf16(pv[2 * g], pv[2 * g + 1]);
#pragma unroll
        for (int ks2 = 0; ks2 < 2; ++ks2) {
          asm("v_permlane32_swap_b32 %0, %1" : "+v"(pq[kb][4 * ks2 + 0]), "+v"(pq[kb][4 * ks2 + 2]));
          asm("v_permlane32_swap_b32 %0, %1" : "+v"(pq[kb][4 * ks2 + 1]), "+v"(pq[kb][4 * ks2 + 3]));
        }
      }
      __builtin_amdgcn_s_setprio(1);
#pragma unroll
      for (int ks = 0; ks < 4; ++ks) {
        bf16x8 pa = *(const bf16x8*)&pq[ks >> 1][(ks & 1) * 4];
        bf16x8 v0 = *(const bf16x8*)(VsW + ks * 512 + l * 8);
        bf16x8 v1 = *(const bf16x8*)(VsW + (4 + ks) * 512 + l * 8);
        o0 = MFMA32(pa, v0, o0);
        o1 = MFMA32(pa, v1, o1);
      }
      __builtin_amdgcn_s_setprio(0);
    }
    __syncthreads();
    cur ^= 1;
  }
  lsum += __shfl_xor(lsum, 32);

  if (wc == 1) {
#pragma unroll
    for (int r = 0; r < 16; ++r) {
      osh[wq * 2048 + r * 64 + l] = o0[r];
      osh[wq * 2048 + (16 + r) * 64 + l] = o1[r];
    }
    lsh[wq * 64 + l] = lsum;
  }
  __syncthreads();
  if (wc == 0) {
    lsum += lsh[wq * 64 + l];
#pragma unroll
    for (int r = 0; r < 16; ++r) {
      o0[r] += osh[wq * 2048 + r * 64 + l];
      o1[r] += osh[wq * 2048 + (16 + r) * 64 + l];
    }
    float linv[16];
#pragma unroll
    for (int r = 0; r < 16; ++r)
      linv[r] = 1.0f / __shfl(lsum, (r & 3) + 8 * (r >> 2) + 4 * lh);
    const int b = hb / 12, h = hb - b * 12;
#pragma unroll
    for (int r = 0; r < 16; ++r) {
      const int row = q0 + (r & 3) + 8 * (r >> 2) + 4 * lh;
      bf16_t* yr = y + ((size_t)b * 4096 + row) * 768 + h * 64 + lq;
      yr[0]  = (bf16_t)(o0[r] * linv[r]);
      yr[32] = (bf16_t)(o1[r] * linv[r]);
    }
  }
}

// ---------------- output GEMM: BK=32 double-buffered, 1 barrier/iter ----------------
__global__ __launch_bounds__(256) void gemm_out(
    const bf16_t* __restrict__ A, const bf16_t* __restrict__ B,
    const float* __restrict__ bias, float* __restrict__ out) {
  __shared__ __align__(16) bf16_t As[2][128 * 32];
  __shared__ __align__(16) bf16_t Bs[2][128 * 32];
  const int K = 768, NKB = 24;
  const int bm = blockIdx.x, bn = blockIdx.y;
  const int tid = threadIdx.x;
  const int w = tid >> 6, l = tid & 63, lg = l >> 4, ln = l & 15;
  const int wr = w >> 1, wc = w & 1;
  const int srow = tid >> 2, sch = tid & 3;
  const int scol = (sch ^ ((srow >> 1) & 3)) << 3;
  const bf16_t* aSrc0 = A + (size_t)(bm * 128 + srow) * K + scol;
  const bf16_t* aSrc1 = A + (size_t)(bm * 128 + 64 + srow) * K + scol;
  const bf16_t* bSrc0 = B + (size_t)(bn * 128 + srow) * K + scol;
  const bf16_t* bSrc1 = B + (size_t)(bn * 128 + 64 + srow) * K + scol;
  f32x4 acc[4][4] = {};
  gld_lds16(aSrc0, &As[0][tid * 8]);
  gld_lds16(aSrc1, &As[0][(256 + tid) * 8]);
  gld_lds16(bSrc0, &Bs[0][tid * 8]);
  gld_lds16(bSrc1, &Bs[0][(256 + tid) * 8]);
  aSrc0 += 32; aSrc1 += 32; bSrc0 += 32; bSrc1 += 32;
  __syncthreads();
  for (int kb = 0; kb < NKB; ++kb) {
    const int cur = kb & 1;
    if (kb + 1 < NKB) {
      gld_lds16(aSrc0, &As[cur ^ 1][tid * 8]);
      gld_lds16(aSrc1, &As[cur ^ 1][(256 + tid) * 8]);
      gld_lds16(bSrc0, &Bs[cur ^ 1][tid * 8]);
      gld_lds16(bSrc1, &Bs[cur ^ 1][(256 + tid) * 8]);
      aSrc0 += 32; aSrc1 += 32; bSrc0 += 32; bSrc1 += 32;
    }
    bf16x8 af[4], bfr[4];
#pragma unroll
    for (int m = 0; m < 4; ++m) {
      const int ra = wr * 64 + m * 16 + ln;
      const int rb = wc * 64 + m * 16 + ln;
      af[m]  = *(const bf16x8*)(&As[cur][ra * 32 + ((lg ^ ((ra >> 1) & 3)) << 3)]);
      bfr[m] = *(const bf16x8*)(&Bs[cur][rb * 32 + ((lg ^ ((rb >> 1) & 3)) << 3)]);
    }
#pragma unroll
    for (int m = 0; m < 4; ++m)
#pragma unroll
      for (int n = 0; n < 4; ++n) acc[m][n] = MFMA16(af[m], bfr[n], acc[m][n]);
    __syncthreads();
  }
  const int gn0 = bn * 128 + wc * 64;
#pragma unroll
  for (int m = 0; m < 4; ++m) {
#pragma unroll
    for (int n = 0; n < 4; ++n) {
#pragma unroll
      for (int j = 0; j < 4; ++j) {
        const int gm = bm * 128 + wr * 64 + m * 16 + lg * 4 + j;
        const int gn = gn0 + n * 16 + ln;
        out[(size_t)gm * 768 + gn] = acc[m][n][j] + bias[gn];
      }
    }
  }
}

// ---------------- launch ----------------
extern "C" void kernel_launch(void* const* d_in, const int* in_sizes, int n_in,
                              void* d_out, int out_size, void* d_ws, size_t ws_size,
                              hipStream_t stream) {
  const float* x  = (const float*)d_in[0];
  const float* Wq = (const float*)d_in[1];
  const float* bq = (const float*)d_in[2];
  const float* Wk = (const float*)d_in[3];
  const float* bk = (const float*)d_in[4];
  const float* Wv = (const float*)d_in[5];
  const float* bv = (const float*)d_in[6];
  const float* Wo = (const float*)d_in[7];
  const float* bo = (const float*)d_in[8];
  float* out = (float*)d_out;

  const int M = 8192, C = 768, QKV = 2304;
  bf16_t* xb   = (bf16_t*)d_ws;                    // [8192][768]
  bf16_t* wqkv = xb + (size_t)M * C;               // [2304][768]
  bf16_t* wob  = wqkv + (size_t)QKV * C;           // [768][768]
  float*  qkvb = (float*)(wob + (size_t)C * C);    // [2304]
  bf16_t* qbuf = (bf16_t*)(qkvb + QKV);            // [B,H,T,D] (q pre-scaled)
  bf16_t* kbuf = qbuf + (size_t)M * C;             // [B,H,T,D]
  bf16_t* vtb  = kbuf + (size_t)M * C;             // [B,H,D,T]
  bf16_t* yb   = xb;                               // reuse xb (dead after gemm_qkv)

  cast_f32_bf16<<<6144, 256, 0, stream>>>(x, xb, M * C);
  prep_w<<<2304, 256, 0, stream>>>(Wq, Wk, Wv, Wo, bq, bk, bv, wqkv, wob, qkvb);

  gemm_qkv<<<dim3(64, 18), 256, 0, stream>>>(xb, wqkv, qkvb, qbuf, kbuf, vtb);
  attn_fwd<<<768, 512, 0, stream>>>(qbuf, kbuf, vtb, yb);
  gemm_out<<<dim3(64, 6), 256, 0, stream>>>(yb, wob, bo, out);
}

// Round 13
// 176.682 us; speedup vs baseline: 1.1721x; 1.0272x over previous
//
#include <hip/hip_runtime.h>

typedef __bf16 bf16_t;
typedef __bf16 bf16x4 __attribute__((ext_vector_type(4)));
typedef __bf16 bf16x8 __attribute__((ext_vector_type(8)));
typedef float  f32x4  __attribute__((ext_vector_type(4)));
typedef float  f32x16 __attribute__((ext_vector_type(16)));
typedef unsigned int u32;

#define MFMA16(a, b, c) __builtin_amdgcn_mfma_f32_16x16x32_bf16((a), (b), (c), 0, 0, 0)
#define MFMA32(a, b, c) __builtin_amdgcn_mfma_f32_32x32x16_bf16((a), (b), (c), 0, 0, 0)

__device__ __forceinline__ void gld_lds16(const bf16_t* g, bf16_t* l) {
  __builtin_amdgcn_global_load_lds((__attribute__((address_space(1))) void*)g,
                                   (__attribute__((address_space(3))) void*)l, 16, 0, 0);
}
__device__ __forceinline__ u32 cvt_pk_bf16(float lo, float hi) {
  u32 r;
  asm("v_cvt_pk_bf16_f32 %0, %1, %2" : "=v"(r) : "v"(lo), "v"(hi));
  return r;
}

// ---------------- prep: x cast (big) ----------------
__global__ void cast_f32_bf16(const float* __restrict__ s, bf16_t* __restrict__ d, int n) {
  int i = (blockIdx.x * blockDim.x + threadIdx.x) * 4;
  if (i >= n) return;
  float4 v = *(const float4*)(s + i);
  bf16x4 o;
  o[0] = (bf16_t)v.x; o[1] = (bf16_t)v.y; o[2] = (bf16_t)v.z; o[3] = (bf16_t)v.w;
  *(bf16x4*)(d + i) = o;
}

// ---------------- prep: all weight casts + bias concat in one launch ----------------
__global__ void prep_w(const float* __restrict__ Wq, const float* __restrict__ Wk,
                       const float* __restrict__ Wv, const float* __restrict__ Wo,
                       const float* __restrict__ bq, const float* __restrict__ bk,
                       const float* __restrict__ bv,
                       bf16_t* __restrict__ wqkv, bf16_t* __restrict__ wob,
                       float* __restrict__ qkvb) {
  const int NW = 768 * 768;
  const int t = blockIdx.x * 256 + threadIdx.x;
  const int i = t * 4;
  if (i < 3 * NW) {
    const float* s; int off;
    if (i < NW)          { s = Wq; off = i; }
    else if (i < 2 * NW) { s = Wk; off = i - NW; }
    else                 { s = Wv; off = i - 2 * NW; }
    float4 v = *(const float4*)(s + off);
    bf16x4 o;
    o[0] = (bf16_t)v.x; o[1] = (bf16_t)v.y; o[2] = (bf16_t)v.z; o[3] = (bf16_t)v.w;
    *(bf16x4*)(wqkv + i) = o;
  } else if (i < 4 * NW) {
    const int off = i - 3 * NW;
    float4 v = *(const float4*)(Wo + off);
    bf16x4 o;
    o[0] = (bf16_t)v.x; o[1] = (bf16_t)v.y; o[2] = (bf16_t)v.z; o[3] = (bf16_t)v.w;
    *(bf16x4*)(wob + off) = o;
  }
  if (t < 2304) qkvb[t] = t < 768 ? bq[t] : (t < 1536 ? bk[t - 768] : bv[t - 1536]);
}

// ---------------- fused QKV GEMM (R9-verified): contiguous staging + chunk-XOR swizzle ----------------
__global__ __launch_bounds__(256) void gemm_qkv(
    const bf16_t* __restrict__ A, const bf16_t* __restrict__ B,
    const float* __restrict__ bias,
    bf16_t* __restrict__ qb, bf16_t* __restrict__ kb2, bf16_t* __restrict__ vtb) {
  __shared__ __align__(16) bf16_t As[128 * 64];
  __shared__ __align__(16) bf16_t Bs[128 * 64];
  const int K = 768;
  const int bm = blockIdx.x, bn = blockIdx.y;
  const int tid = threadIdx.x;
  const int w = tid >> 6, l = tid & 63, lg = l >> 4, ln = l & 15;
  const int wr = w >> 1, wc = w & 1;
  const int lr8 = l >> 3, lc8 = l & 7;
  const int region = (bn * 128) / 768;
  const int ln7 = ln & 7;
  f32x4 acc[4][4] = {};
  for (int kb = 0; kb < K / 64; ++kb) {
    const int k0 = kb * 64;
#pragma unroll
    for (int i = 0; i < 4; ++i) {
      const int row = w * 32 + i * 8 + lr8;
      const int so = k0 + ((lc8 ^ (row & 7)) << 3);     // pre-swizzled source col
      gld_lds16(A + (size_t)(bm * 128 + row) * K + so, As + (w * 32 + i * 8) * 64 + l * 8);
      gld_lds16(B + (size_t)(bn * 128 + row) * K + so, Bs + (w * 32 + i * 8) * 64 + l * 8);
    }
    __syncthreads();
#pragma unroll
    for (int kk = 0; kk < 2; ++kk) {
      bf16x8 af[4], bfr[4];
#pragma unroll
      for (int m = 0; m < 4; ++m) {
        const int jc = ((kk * 4 + lg) ^ ln7) << 3;      // swizzled chunk read
        af[m]  = *(const bf16x8*)(As + (wr * 64 + m * 16 + ln) * 64 + jc);
        bfr[m] = *(const bf16x8*)(Bs + (wc * 64 + m * 16 + ln) * 64 + jc);
      }
      if (region != 2) {
#pragma unroll
        for (int m = 0; m < 4; ++m)
#pragma unroll
          for (int n = 0; n < 4; ++n) acc[m][n] = MFMA16(af[m], bfr[n], acc[m][n]);
      } else {  // C^T for coalesced [B,H,D,T] writes
#pragma unroll
        for (int m = 0; m < 4; ++m)
#pragma unroll
          for (int n = 0; n < 4; ++n) acc[m][n] = MFMA16(bfr[n], af[m], acc[m][n]);
      }
    }
    __syncthreads();
  }
  if (region != 2) {
    const float scl = (region == 0) ? 0.18033688011112042f : 1.0f;  // 0.125*log2(e)
    bf16_t* dst = region == 0 ? qb : kb2;
#pragma unroll
    for (int m = 0; m < 4; ++m)
#pragma unroll
      for (int n = 0; n < 4; ++n)
#pragma unroll
        for (int j = 0; j < 4; ++j) {
          const int gm = bm * 128 + wr * 64 + m * 16 + lg * 4 + j;   // t
          const int gn = bn * 128 + wc * 64 + n * 16 + ln;           // qkv col
          const float v = (acc[m][n][j] + bias[gn]) * scl;
          const int c = gn - region * 768;
          const int bb = gm >> 12, tt = gm & 4095;
          const int hh = c >> 6, d = c & 63;
          dst[((size_t)(bb * 12 + hh) * 4096 + tt) * 64 + d] = (bf16_t)v;
        }
  } else {  // transposed acc: C-row = channel, C-col = t (lanes ln -> consecutive t)
#pragma unroll
    for (int m = 0; m < 4; ++m)
#pragma unroll
      for (int n = 0; n < 4; ++n)
#pragma unroll
        for (int j = 0; j < 4; ++j) {
          const int gn = bn * 128 + wc * 64 + n * 16 + lg * 4 + j;   // qkv col (channel)
          const int gm = bm * 128 + wr * 64 + m * 16 + ln;           // t
          const float v = acc[m][n][j] + bias[gn];
          const int c = gn - 1536;
          const int bb = gm >> 12, tt = gm & 4095;
          const int hh = c >> 6, d = c & 63;
          vtb[((size_t)(bb * 12 + hh) * 64 + d) * 4096 + tt] = (bf16_t)v;
        }
  }
}

// ---------------- flash attention (causal), in-block K-split + MFMA row-sums ----------------
// R9-verified structure; lsum now accumulated as osum = MFMA32(P, ones) on the MFMA
// pipe (4 extra MFMA/tile) instead of 32 VALU adds/tile + end shuffle chain.
// osum C-layout: D[q][n] = row-sum of P replicated across all lanes n -> no shfl needed.
__global__ __launch_bounds__(512) void attn_fwd(
    const bf16_t* __restrict__ q, const bf16_t* __restrict__ k,
    const bf16_t* __restrict__ vt, bf16_t* __restrict__ y) {
  __shared__ __align__(16) unsigned char SMEM[65536];
  bf16_t* Ks = (bf16_t*)SMEM;            // [dbuf][stream][4096]
  bf16_t* Vs = (bf16_t*)(SMEM + 32768);  // [dbuf][stream][4096]
  float*  osh = (float*)SMEM;            // combine: [4][32][64] f32
  float*  lsh = (float*)(SMEM + 32768);  // combine: [4][32] f32 row sums

  const int p = blockIdx.x;
  const int xcd = p & 7, slot = p >> 3;        // 96 slots per XCD
  const int hb = xcd + 8 * (slot % 3);         // 3 heads per XCD (L2-resident K/V)
  const int qt = 31 - slot / 3;                // heavy-first
  const int tid = threadIdx.x;
  const int w = tid >> 6, l = tid & 63, lq = l & 31, lh = l >> 5;
  const int wq = w >> 1, wc = w & 1;
  const size_t hbo = (size_t)hb * (4096 * 64);
  const bf16_t* qh = q + hbo;
  const bf16_t* kh = k + hbo;
  const bf16_t* vh = vt + hbo;

  const int q0 = qt * 128 + wq * 32;           // wave's first q row
  const int qidx = q0 + lq;                    // this lane's q row
  const int nst = qt + 1;                      // lockstep steps

  const int sr = ((tid >> 8) << 5) | (tid & 31);
  const int sc = ((((tid >> 6) & 3) << 1) | ((tid >> 5) & 1)) << 3;
  const bf16_t* k0src = kh + ((size_t)sr * 64 + sc);
  const bf16_t* k1src = k0src + 4096;
  const bf16_t* v0src = vh + ((size_t)sr * 4096 + sc);
  const bf16_t* v1src = v0src + 64;

  bf16x8 qf[4];
#pragma unroll
  for (int ds = 0; ds < 4; ++ds)
    qf[ds] = *(const bf16x8*)(qh + (size_t)qidx * 64 + 16 * ds + 8 * lh);
  bf16x8 ones;
#pragma unroll
  for (int j = 0; j < 8; ++j) ones[j] = (bf16_t)1.0f;

  gld_lds16(k0src, Ks + tid * 8);
  gld_lds16(k1src, Ks + 4096 + tid * 8);
  gld_lds16(v0src, Vs + tid * 8);
  gld_lds16(v1src, Vs + 4096 + tid * 8);
  __syncthreads();

  f32x16 o0 = {}, o1 = {}, osum = {};

  int cur = 0;
  for (int i = 0; i < nst; ++i) {
    if (i + 1 < nst) {
      bf16_t* kd = Ks + (cur ^ 1) * 8192;
      bf16_t* vd = Vs + (cur ^ 1) * 8192;
      gld_lds16(k0src + 8192, kd + tid * 8);
      gld_lds16(k1src + 8192, kd + 4096 + tid * 8);
      gld_lds16(v0src + 128, vd + tid * 8);
      gld_lds16(v1src + 128, vd + 4096 + tid * 8);
    }
    k0src += 8192; k1src += 8192; v0src += 128; v1src += 128;
    const int t = 2 * i + wc;
    if (t * 64 <= q0 + 31) {
      const int kvb = t * 64;
      const bool diag = (kvb + 63 > q0);
      const bf16_t* KsW = Ks + (cur * 2 + wc) * 4096;
      const bf16_t* VsW = Vs + (cur * 2 + wc) * 4096;
      u32 pq[2][8];
#pragma unroll
      for (int kb = 0; kb < 2; ++kb) {
        f32x16 st = {};
        __builtin_amdgcn_s_setprio(1);
#pragma unroll
        for (int ds = 0; ds < 4; ++ds) {
          bf16x8 kf = *(const bf16x8*)(KsW + (kb * 4 + ds) * 512 + l * 8);
          st = MFMA32(kf, qf[ds], st);
        }
        __builtin_amdgcn_s_setprio(0);
        float pv[16];
#pragma unroll
        for (int r = 0; r < 16; ++r) pv[r] = __builtin_amdgcn_exp2f(st[r]);
        if (diag) {
          const int kb0 = kvb + kb * 32 + 4 * lh;
#pragma unroll
          for (int r = 0; r < 16; ++r)
            if (kb0 + (r & 3) + 8 * (r >> 2) > qidx) pv[r] = 0.f;
        }
#pragma unroll
        for (int g = 0; g < 8; ++g) pq[kb][g] = cvt_pk_bf16(pv[2 * g], pv[2 * g + 1]);
#pragma unroll
        for (int ks2 = 0; ks2 < 2; ++ks2) {
          asm("v_permlane32_swap_b32 %0, %1" : "+v"(pq[kb][4 * ks2 + 0]), "+v"(pq[kb][4 * ks2 + 2]));
          asm("v_permlane32_swap_b32 %0, %1" : "+v"(pq[kb][4 * ks2 + 1]), "+v"(pq[kb][4 * ks2 + 3]));
        }
      }
      __builtin_amdgcn_s_setprio(1);
#pragma unroll
      for (int ks = 0; ks < 4; ++ks) {
        bf16x8 pa = *(const bf16x8*)&pq[ks >> 1][(ks & 1) * 4];
        bf16x8 v0 = *(const bf16x8*)(VsW + ks * 512 + l * 8);
        bf16x8 v1 = *(const bf16x8*)(VsW + (4 + ks) * 512 + l * 8);
        o0 = MFMA32(pa, v0, o0);
        o1 = MFMA32(pa, v1, o1);
        osum = MFMA32(pa, ones, osum);   // row-sums of P on the MFMA pipe
      }
      __builtin_amdgcn_s_setprio(0);
    }
    __syncthreads();
    cur ^= 1;
  }

  if (wc == 1) {
#pragma unroll
    for (int r = 0; r < 16; ++r) {
      osh[wq * 2048 + r * 64 + l] = o0[r];
      osh[wq * 2048 + (16 + r) * 64 + l] = o1[r];
    }
    if (lq == 0) {
#pragma unroll
      for (int r = 0; r < 16; ++r)
        lsh[wq * 32 + (r & 3) + 8 * (r >> 2) + 4 * lh] = osum[r];
    }
  }
  __syncthreads();
  if (wc == 0) {
#pragma unroll
    for (int r = 0; r < 16; ++r) {
      o0[r] += osh[wq * 2048 + r * 64 + l];
      o1[r] += osh[wq * 2048 + (16 + r) * 64 + l];
    }
    float linv[16];
#pragma unroll
    for (int r = 0; r < 16; ++r) {
      const int rl = (r & 3) + 8 * (r >> 2) + 4 * lh;
      linv[r] = 1.0f / (osum[r] + lsh[wq * 32 + rl]);
    }
    const int b = hb / 12, h = hb - b * 12;
#pragma unroll
    for (int r = 0; r < 16; ++r) {
      const int row = q0 + (r & 3) + 8 * (r >> 2) + 4 * lh;
      bf16_t* yr = y + ((size_t)b * 4096 + row) * 768 + h * 64 + lq;
      yr[0]  = (bf16_t)(o0[r] * linv[r]);
      yr[32] = (bf16_t)(o1[r] * linv[r]);
    }
  }
}

// ---------------- output GEMM: out = y @ Wo^T + bo (fp32), swizzled LDS (R9-verified) ----------------
__global__ __launch_bounds__(256) void gemm_out(
    const bf16_t* __restrict__ A, const bf16_t* __restrict__ B,
    const float* __restrict__ bias, float* __restrict__ out) {
  __shared__ __align__(16) bf16_t As[128 * 64];
  __shared__ __align__(16) bf16_t Bs[128 * 64];
  const int K = 768;
  const int bm = blockIdx.x, bn = blockIdx.y;
  const int tid = threadIdx.x;
  const int w = tid >> 6, l = tid & 63, lg = l >> 4, ln = l & 15;
  const int wr = w >> 1, wc = w & 1;
  const int lr8 = l >> 3, lc8 = l & 7;
  const int ln7 = ln & 7;
  f32x4 acc[4][4] = {};
  for (int kb = 0; kb < K / 64; ++kb) {
    const int k0 = kb * 64;
#pragma unroll
    for (int i = 0; i < 4; ++i) {
      const int row = w * 32 + i * 8 + lr8;
      const int so = k0 + ((lc8 ^ (row & 7)) << 3);
      gld_lds16(A + (size_t)(bm * 128 + row) * K + so, As + (w * 32 + i * 8) * 64 + l * 8);
      gld_lds16(B + (size_t)(bn * 128 + row) * K + so, Bs + (w * 32 + i * 8) * 64 + l * 8);
    }
    __syncthreads();
#pragma unroll
    for (int kk = 0; kk < 2; ++kk) {
      bf16x8 af[4], bfr[4];
#pragma unroll
      for (int m = 0; m < 4; ++m) {
        const int jc = ((kk * 4 + lg) ^ ln7) << 3;
        af[m]  = *(const bf16x8*)(As + (wr * 64 + m * 16 + ln) * 64 + jc);
        bfr[m] = *(const bf16x8*)(Bs + (wc * 64 + m * 16 + ln) * 64 + jc);
      }
#pragma unroll
      for (int m = 0; m < 4; ++m)
#pragma unroll
        for (int n = 0; n < 4; ++n) acc[m][n] = MFMA16(af[m], bfr[n], acc[m][n]);
    }
    __syncthreads();
  }
  const int gn0 = bn * 128 + wc * 64;
#pragma unroll
  for (int m = 0; m < 4; ++m) {
#pragma unroll
    for (int n = 0; n < 4; ++n) {
#pragma unroll
      for (int j = 0; j < 4; ++j) {
        const int gm = bm * 128 + wr * 64 + m * 16 + lg * 4 + j;
        const int gn = gn0 + n * 16 + ln;
        out[(size_t)gm * 768 + gn] = acc[m][n][j] + bias[gn];
      }
    }
  }
}

// ---------------- launch ----------------
extern "C" void kernel_launch(void* const* d_in, const int* in_sizes, int n_in,
                              void* d_out, int out_size, void* d_ws, size_t ws_size,
                              hipStream_t stream) {
  const float* x  = (const float*)d_in[0];
  const float* Wq = (const float*)d_in[1];
  const float* bq = (const float*)d_in[2];
  const float* Wk = (const float*)d_in[3];
  const float* bk = (const float*)d_in[4];
  const float* Wv = (const float*)d_in[5];
  const float* bv = (const float*)d_in[6];
  const float* Wo = (const float*)d_in[7];
  const float* bo = (const float*)d_in[8];
  float* out = (float*)d_out;

  const int M = 8192, C = 768, QKV = 2304;
  bf16_t* xb   = (bf16_t*)d_ws;                    // [8192][768]
  bf16_t* wqkv = xb + (size_t)M * C;               // [2304][768]
  bf16_t* wob  = wqkv + (size_t)QKV * C;           // [768][768]
  float*  qkvb = (float*)(wob + (size_t)C * C);    // [2304]
  bf16_t* qbuf = (bf16_t*)(qkvb + QKV);            // [B,H,T,D] (q pre-scaled)
  bf16_t* kbuf = qbuf + (size_t)M * C;             // [B,H,T,D]
  bf16_t* vtb  = kbuf + (size_t)M * C;             // [B,H,D,T]
  bf16_t* yb   = xb;                               // reuse xb (dead after gemm_qkv)

  cast_f32_bf16<<<6144, 256, 0, stream>>>(x, xb, M * C);
  prep_w<<<2304, 256, 0, stream>>>(Wq, Wk, Wv, Wo, bq, bk, bv, wqkv, wob, qkvb);

  gemm_qkv<<<dim3(64, 18), 256, 0, stream>>>(xb, wqkv, qkvb, qbuf, kbuf, vtb);
  attn_fwd<<<768, 512, 0, stream>>>(qbuf, kbuf, vtb, yb);
  gemm_out<<<dim3(64, 6), 256, 0, stream>>>(yb, wob, bo, out);
}